// Round 1
// 254.031 us; speedup vs baseline: 1.0087x; 1.0087x over previous
//
#include <hip/hip_runtime.h>

#define Bb 16
#define Ll 2048
#define Hh 768
#define Dd 64
#define Cc 64
#define HC 64             // h-tile width (256 B rows -> full-line coalesced out stores)
#define NT (Hh / HC)      // 12 h-tiles
#define NCH (Ll / Cc)     // 32 chunks
#define PSEG 8            // parallel scan segments
#define CPS (NCH / PSEG)  // 4 chunks per segment
#define NHT (HC / 16)     // 4 MFMA col-tiles per h-tile

typedef __attribute__((ext_vector_type(8))) short bf16x8;
typedef __attribute__((ext_vector_type(4))) float f32x4;

__device__ __forceinline__ short f2bf(float f) {
  union { float f; unsigned u; } c;
  c.f = f;
  unsigned r = (c.u + 0x7FFFu + ((c.u >> 16) & 1u)) >> 16;
  return (short)r;
}
__device__ __forceinline__ unsigned pack2(float a, float b) {
  return (unsigned)(unsigned short)f2bf(a) | ((unsigned)(unsigned short)f2bf(b) << 16);
}
__device__ __forceinline__ float bf2f(short s) {
  union { unsigned u; float f; } c;
  c.u = ((unsigned)(unsigned short)s) << 16;
  return c.f;
}

// CK-style barrier: waits LDS ops only; global loads stay in flight.
__device__ __forceinline__ void sync_lds() {
  asm volatile("s_waitcnt lgkmcnt(0)\n\ts_barrier" ::: "memory");
}

// ---------------- Prep: per (b,chunk) -> bf16 E[64][64], FT[64][64], scT[64][64] ----------------
__global__ __launch_bounds__(256) void prep_kernel(const int* __restrict__ x,
                                                   const float* __restrict__ ae,
                                                   const float* __restrict__ w,
                                                   short* __restrict__ Eg,
                                                   short* __restrict__ FTg,
                                                   short* __restrict__ scTg) {
  const int tid = threadIdx.x;
  const int wv = tid >> 6, lane = tid & 63, quad = lane >> 4, lq = lane & 15;
  const int b = blockIdx.x >> 5, ch = blockIdx.x & 31;
  const size_t gb = (size_t)blockIdx.x * 4096;
  __shared__ short sE[64 * 64];   // rows i, cols d (swizzled)
  __shared__ short sWT[64 * 64];  // rows e, cols d (swizzled) = w^T
  __shared__ short sF[64 * 64];   // rows i, cols e (swizzled)

  // gather E rows -> sE + Eg;  stage w^T
  {
    const int i = tid >> 2, seg = tid & 3;
    const int idx = x[b * Ll + ch * Cc + i];
    const float4* aer = (const float4*)(ae + (size_t)idx * Dd) + seg * 4;
    float4 ev[4];
#pragma unroll
    for (int q = 0; q < 4; ++q) ev[q] = aer[q];
    uint4 pA, pB;
    pA.x = pack2(ev[0].x, ev[0].y); pA.y = pack2(ev[0].z, ev[0].w);
    pA.z = pack2(ev[1].x, ev[1].y); pA.w = pack2(ev[1].z, ev[1].w);
    pB.x = pack2(ev[2].x, ev[2].y); pB.y = pack2(ev[2].z, ev[2].w);
    pB.z = pack2(ev[3].x, ev[3].y); pB.w = pack2(ev[3].z, ev[3].w);
    *(uint4*)&sE[i * 64 + (((2 * seg) ^ (i & 7)) << 3)] = pA;
    *(uint4*)&sE[i * 64 + (((2 * seg + 1) ^ (i & 7)) << 3)] = pB;
    *(uint4*)(Eg + gb + i * 64 + seg * 16) = pA;
    *(uint4*)(Eg + gb + i * 64 + seg * 16 + 8) = pB;
    const float4* wr = (const float4*)w;
#pragma unroll
    for (int q = 0; q < 4; ++q) {
      const int fl = q * 256 + tid;
      const int d = fl >> 4, es = (fl & 15) * 4;
      const float4 v = wr[fl];
      const float vv[4] = {v.x, v.y, v.z, v.w};
#pragma unroll
      for (int c = 0; c < 4; ++c) {
        const int e = es + c;
        sWT[e * 64 + (((d >> 3) ^ (e & 7)) << 3) + (d & 7)] = f2bf(vv[c]);
      }
    }
  }
  __syncthreads();

  const int rm = wv * 16 + lq;
  bf16x8 aE[2], aW[2];
#pragma unroll
  for (int ks = 0; ks < 2; ++ks) {
    const int blk = ((ks * 4 + quad) ^ (rm & 7)) << 3;
    aE[ks] = *(const bf16x8*)&sE[rm * 64 + blk];
    aW[ks] = *(const bf16x8*)&sWT[rm * 64 + blk];
  }

  // F[i][e] = sum_d E[i][d] w[d][e]  -> sF ;  FT[e][i] -> FTg
#pragma unroll
  for (int nt = 0; nt < 4; ++nt) {
    const int rn = nt * 16 + lq;
    f32x4 accF = {}, accT = {};
#pragma unroll
    for (int ks = 0; ks < 2; ++ks) {
      const int blk = ((ks * 4 + quad) ^ (rn & 7)) << 3;
      const bf16x8 bW = *(const bf16x8*)&sWT[rn * 64 + blk];
      const bf16x8 bE = *(const bf16x8*)&sE[rn * 64 + blk];
      accF = __builtin_amdgcn_mfma_f32_16x16x32_bf16(aE[ks], bW, accF, 0, 0, 0);
      accT = __builtin_amdgcn_mfma_f32_16x16x32_bf16(aW[ks], bE, accT, 0, 0, 0);
    }
#pragma unroll
    for (int r = 0; r < 4; ++r) {
      const int i = wv * 16 + quad * 4 + r;   // m of accF
      const int e = nt * 16 + lq;
      sF[i * 64 + (((e >> 3) ^ (i & 7)) << 3) + (e & 7)] = f2bf(accF[r]);
      const int e2 = wv * 16 + quad * 4 + r;  // m of accT
      const int i2 = nt * 16 + lq;
      FTg[gb + e2 * 64 + i2] = f2bf(accT[r]);
    }
  }
  __syncthreads();

  // sc[j][i] = sum_e E[j][e] F[i][e], strict mask i<j -> scTg rows j
#pragma unroll
  for (int nt = 0; nt < 4; ++nt) {
    const int rn = nt * 16 + lq;
    f32x4 acc = {};
#pragma unroll
    for (int ks = 0; ks < 2; ++ks) {
      const int blk = ((ks * 4 + quad) ^ (rn & 7)) << 3;
      const bf16x8 bF = *(const bf16x8*)&sF[rn * 64 + blk];
      acc = __builtin_amdgcn_mfma_f32_16x16x32_bf16(aE[ks], bF, acc, 0, 0, 0);
    }
#pragma unroll
    for (int r = 0; r < 4; ++r) {
      const int j = wv * 16 + quad * 4 + r;
      const int i = nt * 16 + lq;
      scTg[gb + j * 64 + i] = f2bf(i < j ? acc[r] : 0.f);
    }
  }
}

// ---------------- State: per (tile, b, seg<PSEG-1) local segment state ----------------
// S_loc[b][seg][h][d] = sum over i in segment of (i+1)*bx[b,i,h] * FT[d][i]
__global__ __launch_bounds__(256) void state_kernel(const float* __restrict__ bx,
                                                    const short* __restrict__ FTg,
                                                    short* __restrict__ Sg) {
  const int tile = blockIdx.x, b = blockIdx.y, seg = blockIdx.z;
  const int tid = threadIdx.x;
  const int w = tid >> 6, lane = tid & 63, quad = lane >> 4, lq = lane & 15;
  const int ip = tid & 31, hg = tid >> 5;
  const int rj = w * 16 + lq;

  __shared__ short sGT[2][HC * 64];

  f32x4 accS[NHT] = {};
  float2 rG[2 * NHT];
  bf16x8 bD[2];

  auto load_G = [&](int ch) {
    const float* xr = bx + ((size_t)(b * Ll) + ch * Cc + 2 * ip) * Hh + tile * HC + hg * 8;
#pragma unroll
    for (int k = 0; k < NHT; ++k) {
      rG[k] = *(const float2*)(xr + 2 * k);
      rG[NHT + k] = *(const float2*)(xr + Hh + 2 * k);
    }
  };
  auto load_D = [&](int ch) {
    const size_t tb = (size_t)(b * NCH + ch) * 4096;
#pragma unroll
    for (int ks = 0; ks < 2; ++ks)
      bD[ks] = *(const bf16x8*)(FTg + tb + rj * 64 + (ks * 4 + quad) * 8);
  };

  load_G(seg * CPS);
  load_D(seg * CPS);

#pragma unroll
  for (int c = 0; c < CPS; ++c) {
    const int ch = seg * CPS + c;
    const int cur = c & 1;
    const int p0 = ch * Cc;
    // stage G^T (scaled bx, transposed h x i) into LDS
    {
      const float s0 = (float)(p0 + 2 * ip + 1), s1 = (float)(p0 + 2 * ip + 2);
#pragma unroll
      for (int k = 0; k < NHT; ++k)
#pragma unroll
        for (int cc = 0; cc < 2; ++cc) {
          const int h = hg * 8 + 2 * k + cc;
          const float g0 = (cc ? rG[k].y : rG[k].x) * s0;
          const float g1 = (cc ? rG[NHT + k].y : rG[NHT + k].x) * s1;
          const int sa = h * 64 + (((ip >> 2) ^ (h & 7)) << 3) + 2 * (ip & 3);
          *(unsigned*)&sGT[cur][sa] = pack2(g0, g1);
        }
    }
    if (c + 1 < CPS) load_G(ch + 1);
    sync_lds();  // one barrier/chunk: double-buffered sGT
#pragma unroll
    for (int ht = 0; ht < NHT; ++ht) {
      const int rh = ht * 16 + lq;
#pragma unroll
      for (int ks = 0; ks < 2; ++ks) {
        const int blk = ((ks * 4 + quad) ^ (rh & 7)) << 3;
        const bf16x8 g = *(const bf16x8*)&sGT[cur][rh * 64 + blk];
        accS[ht] = __builtin_amdgcn_mfma_f32_16x16x32_bf16(g, bD[ks], accS[ht], 0, 0, 0);
      }
    }
    if (c + 1 < CPS) load_D(ch + 1);  // prefetch after consumption (no double-buffer needed)
  }

  short* Sr = Sg + (size_t)(b * (PSEG - 1) + seg) * (Hh * 64);
#pragma unroll
  for (int ht = 0; ht < NHT; ++ht)
#pragma unroll
    for (int r = 0; r < 4; ++r) {
      const int h = tile * HC + ht * 16 + quad * 4 + r;
      Sr[h * 64 + w * 16 + lq] = f2bf(accS[ht][r]);
    }
}

// ---------------- Scan: per (tile, b, seg) — 4-chunk segment with prefix-state init ----------------
__global__ __launch_bounds__(256) void scan_kernel(const float* __restrict__ bx,
                                                   const short* __restrict__ Eg,
                                                   const short* __restrict__ FTg,
                                                   const short* __restrict__ scTg,
                                                   const short* __restrict__ Sg,
                                                   float* __restrict__ out) {
  const int tile = blockIdx.x, b = blockIdx.y, seg = blockIdx.z;
  const int tid = threadIdx.x;
  const int w = tid >> 6, lane = tid & 63, quad = lane >> 4, lq = lane & 15;
  const int ip = tid & 31, hg = tid >> 5;
  const int rj = w * 16 + lq;

  __shared__ short sGT[2][HC * 64];
  __shared__ short sST[2][HC * 64];

  f32x4 accS[NHT] = {};
  bf16x8 aC1[2], aC2[2], bD[2];  // scT / E / FT fragments, loaded straight from global
  float2 rG[2 * NHT];

  auto load_G = [&](int ch) {
    const float* xr = bx + ((size_t)(b * Ll) + ch * Cc + 2 * ip) * Hh + tile * HC + hg * 8;
#pragma unroll
    for (int k = 0; k < NHT; ++k) {
      rG[k] = *(const float2*)(xr + 2 * k);
      rG[NHT + k] = *(const float2*)(xr + Hh + 2 * k);
    }
  };
  auto load_frag = [&](int ch) {
    const size_t tb = (size_t)(b * NCH + ch) * 4096;
#pragma unroll
    for (int ks = 0; ks < 2; ++ks) {
      const int o = rj * 64 + (ks * 4 + quad) * 8;
      aC1[ks] = *(const bf16x8*)(scTg + tb + o);
      aC2[ks] = *(const bf16x8*)(Eg + tb + o);
      bD[ks]  = *(const bf16x8*)(FTg + tb + o);
    }
  };

  // issue chunk-0 loads first; their latency overlaps the prefix-state gather below
  load_G(seg * CPS);
  load_frag(seg * CPS);

  // init accS with exclusive prefix of segment states (bf16 -> f32 accumulate)
  for (int s = 0; s < seg; ++s) {
    const short* Sr = Sg + (size_t)(b * (PSEG - 1) + s) * (Hh * 64);
#pragma unroll
    for (int ht = 0; ht < NHT; ++ht)
#pragma unroll
      for (int r = 0; r < 4; ++r) {
        const int h = tile * HC + ht * 16 + quad * 4 + r;
        accS[ht][r] += bf2f(Sr[h * 64 + w * 16 + lq]);
      }
  }

#pragma unroll
  for (int c = 0; c < CPS; ++c) {
    const int ch = seg * CPS + c;
    const int cur = c & 1;
    const int p0 = ch * Cc;
    // stage G^T
    {
      const float s0 = (float)(p0 + 2 * ip + 1), s1 = (float)(p0 + 2 * ip + 2);
#pragma unroll
      for (int k = 0; k < NHT; ++k)
#pragma unroll
        for (int cc = 0; cc < 2; ++cc) {
          const int h = hg * 8 + 2 * k + cc;
          const float g0 = (cc ? rG[k].y : rG[k].x) * s0;
          const float g1 = (cc ? rG[NHT + k].y : rG[NHT + k].x) * s1;
          const int sa = h * 64 + (((ip >> 2) ^ (h & 7)) << 3) + 2 * (ip & 3);
          *(unsigned*)&sGT[cur][sa] = pack2(g0, g1);
        }
    }
    // stage S^T (state after chunks < ch)
#pragma unroll
    for (int ht = 0; ht < NHT; ++ht)
#pragma unroll
      for (int r = 0; r < 4; ++r) {
        const int h = ht * 16 + quad * 4 + r;
        const int d = w * 16 + lq;
        sST[cur][h * 64 + (((d >> 3) ^ (h & 7)) << 3) + (d & 7)] = f2bf(accS[ht][r]);
      }
    if (c + 1 < CPS) load_G(ch + 1);
    sync_lds();  // single barrier per chunk (double-buffered LDS)

    f32x4 accO[NHT] = {};
#pragma unroll
    for (int ht = 0; ht < NHT; ++ht) {
      const int rh = ht * 16 + lq;
#pragma unroll
      for (int ks = 0; ks < 2; ++ks) {
        const int blk = ((ks * 4 + quad) ^ (rh & 7)) << 3;
        const bf16x8 g  = *(const bf16x8*)&sGT[cur][rh * 64 + blk];
        const bf16x8 st = *(const bf16x8*)&sST[cur][rh * 64 + blk];
        accO[ht] = __builtin_amdgcn_mfma_f32_16x16x32_bf16(aC1[ks], g,  accO[ht], 0, 0, 0);
        accO[ht] = __builtin_amdgcn_mfma_f32_16x16x32_bf16(aC2[ks], st, accO[ht], 0, 0, 0);
        accS[ht] = __builtin_amdgcn_mfma_f32_16x16x32_bf16(g, bD[ks],  accS[ht], 0, 0, 0);
      }
    }
    if (c + 1 < CPS) load_frag(ch + 1);  // prefetch after consumption

    // epilogue: out = bx + accO/(j+1); 256 B-aligned full-line stores per row
#pragma unroll
    for (int ht = 0; ht < NHT; ++ht)
#pragma unroll
      for (int r = 0; r < 4; ++r) {
        const int gj = p0 + w * 16 + quad * 4 + r;
        const size_t off = ((size_t)(b * Ll) + gj) * Hh + tile * HC + ht * 16 + lq;
        out[off] = bx[off] + accO[ht][r] * (1.0f / (float)(gj + 1));
      }
  }
}

extern "C" void kernel_launch(void* const* d_in, const int* in_sizes, int n_in,
                              void* d_out, int out_size, void* d_ws, size_t ws_size,
                              hipStream_t stream) {
  (void)in_sizes; (void)n_in; (void)out_size; (void)ws_size;
  const float* bx = (const float*)d_in[0];
  const int* x = (const int*)d_in[1];
  const float* ae = (const float*)d_in[2];
  const float* w = (const float*)d_in[3];
  float* out = (float*)d_out;
  short* Eg = (short*)d_ws;                       // 512*4096 bf16 = 4 MB
  short* FTg = Eg + (size_t)512 * 4096;           // 4 MB
  short* scTg = FTg + (size_t)512 * 4096;         // 4 MB
  short* Sg = scTg + (size_t)512 * 4096;          // 16*7*768*64 bf16 = 11 MB

  prep_kernel<<<Bb * NCH, 256, 0, stream>>>(x, ae, w, Eg, FTg, scTg);
  dim3 gst(NT, Bb, PSEG - 1);
  state_kernel<<<gst, 256, 0, stream>>>(bx, FTg, Sg);
  dim3 gsc(NT, Bb, PSEG);
  scan_kernel<<<gsc, 256, 0, stream>>>(bx, Eg, FTg, scTg, Sg, out);
}